// Round 1
// baseline (439.477 us; speedup 1.0000x reference)
//
#include <hip/hip_runtime.h>

typedef __bf16 bf16x8 __attribute__((ext_vector_type(8)));
typedef float  f32x4  __attribute__((ext_vector_type(4)));

#define LOG2E 1.4426950408889634f

__device__ __forceinline__ float fexp(float x){ return __builtin_amdgcn_exp2f(x * LOG2E); }
__device__ __forceinline__ float sigm(float x){ return __builtin_amdgcn_rcpf(1.0f + fexp(-x)); }
__device__ __forceinline__ float ftanh(float x){
  float ax = fabsf(x);
  float e  = fexp(-2.0f * ax);
  float t  = (1.0f - e) * __builtin_amdgcn_rcpf(1.0f + e);
  return copysignf(t, x);
}
__device__ __forceinline__ f32x4 MFMA(bf16x8 a, bf16x8 b, f32x4 c){
  return __builtin_amdgcn_mfma_f32_16x16x32_bf16(a, b, c, 0, 0, 0);
}

// B=2048, T=128, D=32, H=256, S=39, PM=12
// 128 workgroups x 512 threads; each wg owns 16 batch rows for the whole sequence.
__global__ __launch_bounds__(512, 2) void ealstm_kernel(
    const float* __restrict__ x,      const float* __restrict__ latlons,
    const float* __restrict__ yearly, const float* __restrict__ pm,
    const float* __restrict__ Wf_i, const float* __restrict__ Wf_h, const float* __restrict__ bf_h,
    const float* __restrict__ Wu,   const float* __restrict__ bu,
    const float* __restrict__ Wg_i, const float* __restrict__ Wg_h, const float* __restrict__ bg_h,
    const float* __restrict__ Wo_i, const float* __restrict__ Wo_h, const float* __restrict__ bo_h,
    const float* __restrict__ Wd0,  const float* __restrict__ bd0,
    const float* __restrict__ Wd1,  const float* __restrict__ bd1,
    float* __restrict__ out)
{
  // LDS: 16896 + 2048 + 98304 + 4096 = 121344 B
  __shared__ __align__(16) __bf16 hbuf[2][16*264];   // h state, double buffered, row-major stride 264 (pad vs bank clash)
  __shared__ __align__(16) __bf16 xbuf[2][16*32];    // x_t tile, double buffered
  __shared__ __align__(16) __bf16 wlds[48*2*512];    // B-frags for K-tile7 (h cols 224..255) and K-tile8 (x), all 48 col-tiles
  __shared__ __align__(16) float  xs[16*64];         // [latlons|yearly|0pad] padded to K=64

  const int tid  = threadIdx.x;
  const int w    = tid >> 6;      // wave 0..7
  const int lane = tid & 63;
  const int q    = lane >> 4;     // quad 0..3
  const int l    = lane & 15;
  const int wgb  = blockIdx.x * 16;

  const float* Wh[3] = {Wf_h, Wg_h, Wo_h};
  const float* Wi[3] = {Wf_i, Wg_i, Wo_i};
  const float* bH[3] = {bf_h, bg_h, bo_h};

  // ---------------- init: LDS fills ----------------
  for(int idx = tid; idx < 16*64; idx += 512){
    int m = idx >> 6, k = idx & 63;
    int b = wgb + m;
    float v = 0.0f;
    if(k < 2) v = latlons[b*2 + k];
    else if(k < 39) v = yearly[b*37 + (k-2)];
    xs[idx] = v;
  }
  for(int idx = tid; idx < 16*264; idx += 512) hbuf[0][idx] = (__bf16)0.0f;
  {
    int m = tid >> 5, k = tid & 31;   // 512 threads == 16*32 elems
    xbuf[0][tid] = (__bf16)x[(size_t)(wgb + m)*4096 + k];   // t = 0
  }
  // wlds: frag(ct,kk): ct = gate*16 + ntile_global; kk=0 -> Wh cols k=224..255 ; kk=1 -> Wi (x) k=0..31
  for(int grp = tid; grp < 48*2*64; grp += 512){
    int ct  = grp >> 7;
    int rem = grp & 127;
    int kk  = rem >> 6;
    int ln  = rem & 63;
    int q2 = ln >> 4, l2 = ln & 15;
    int gate = ct >> 4;
    int colc = (ct & 15)*16 + l2;
    const float* p = (kk == 0) ? (Wh[gate] + colc*256 + 224 + q2*8)
                               : (Wi[gate] + colc*32  + q2*8);
    bf16x8 v;
    #pragma unroll
    for(int j=0;j<8;j++) v[j] = (__bf16)p[j];
    *(bf16x8*)&wlds[(ct*2 + kk)*512 + ln*8] = v;
  }

  // ---------------- init: VGPR-resident recurrent weights (K-tiles 0..6) ----------------
  bf16x8 wreg[3][2][7];
  #pragma unroll
  for(int g=0; g<3; g++){
    #pragma unroll
    for(int n=0; n<2; n++){
      int colc = w*32 + n*16 + l;
      #pragma unroll
      for(int kt=0; kt<7; kt++){
        const float* p = Wh[g] + colc*256 + kt*32 + q*8;
        f32x4 v0 = *(const f32x4*)p;
        f32x4 v1 = *(const f32x4*)(p + 4);
        bf16x8 v;
        v[0]=(__bf16)v0[0]; v[1]=(__bf16)v0[1]; v[2]=(__bf16)v0[2]; v[3]=(__bf16)v0[3];
        v[4]=(__bf16)v1[0]; v[5]=(__bf16)v1[1]; v[6]=(__bf16)v1[2]; v[7]=(__bf16)v1[3];
        wreg[g][n][kt] = v;
      }
    }
  }
  float biasv[3][2];
  float buv[2];
  #pragma unroll
  for(int g=0; g<3; g++){
    #pragma unroll
    for(int n=0; n<2; n++) biasv[g][n] = bH[g][w*32 + n*16 + l];
  }
  #pragma unroll
  for(int n=0; n<2; n++) buv[n] = bu[w*32 + n*16 + l];

  __syncthreads();

  // ---------------- i_gate = sigmoid(x_s @ Wu^T + bu), via MFMA (K padded to 64) ----------------
  f32x4 ig[2];
  {
    f32x4 iga[2]; 
    f32x4 z4 = {0.f,0.f,0.f,0.f};
    iga[0] = z4; iga[1] = z4;
    #pragma unroll
    for(int kt=0; kt<2; kt++){
      bf16x8 a;
      const float* xr = &xs[l*64 + kt*32 + q*8];
      #pragma unroll
      for(int j=0;j<8;j++) a[j] = (__bf16)xr[j];
      #pragma unroll
      for(int n=0;n<2;n++){
        int colc = w*32 + n*16 + l;
        bf16x8 b;
        #pragma unroll
        for(int j=0;j<8;j++){
          int k = kt*32 + q*8 + j;
          b[j] = (__bf16)((k < 39) ? Wu[colc*39 + k] : 0.0f);
        }
        iga[n] = MFMA(a, b, iga[n]);
      }
    }
    #pragma unroll
    for(int n=0;n<2;n++){
      #pragma unroll
      for(int i=0;i<4;i++) ig[n][i] = sigm(iga[n][i] + buv[n]);
    }
  }

  f32x4 cst[2];
  {
    f32x4 z4 = {0.f,0.f,0.f,0.f};
    cst[0] = z4; cst[1] = z4;
  }

  // ---------------- recurrence: 128 steps, 1 barrier/step ----------------
  for(int t = 0; t < 128; t++){
    const int cur = t & 1;
    f32x4 acc[3][2];
    {
      f32x4 z4 = {0.f,0.f,0.f,0.f};
      #pragma unroll
      for(int g=0;g<3;g++){ acc[g][0]=z4; acc[g][1]=z4; }
    }
    // h K-tiles 0..6 (weights in VGPRs)
    #pragma unroll
    for(int kt=0; kt<7; kt++){
      bf16x8 a = *(const bf16x8*)&hbuf[cur][l*264 + kt*32 + q*8];
      #pragma unroll
      for(int g=0;g<3;g++){
        #pragma unroll
        for(int n=0;n<2;n++) acc[g][n] = MFMA(a, wreg[g][n][kt], acc[g][n]);
      }
    }
    // h K-tile 7 (weights from LDS)
    {
      bf16x8 a7 = *(const bf16x8*)&hbuf[cur][l*264 + 7*32 + q*8];
      #pragma unroll
      for(int g=0;g<3;g++){
        #pragma unroll
        for(int n=0;n<2;n++){
          bf16x8 bw = *(const bf16x8*)&wlds[((g*16 + (w*2+n))*2 + 0)*512 + lane*8];
          acc[g][n] = MFMA(a7, bw, acc[g][n]);
        }
      }
    }
    // x K-tile (weights from LDS)
    {
      bf16x8 ax = *(const bf16x8*)&xbuf[cur][l*32 + q*8];
      #pragma unroll
      for(int g=0;g<3;g++){
        #pragma unroll
        for(int n=0;n<2;n++){
          bf16x8 bw = *(const bf16x8*)&wlds[((g*16 + (w*2+n))*2 + 1)*512 + lane*8];
          acc[g][n] = MFMA(ax, bw, acc[g][n]);
        }
      }
    }
    // wave 7: stage x_{t+1}
    if(w == 7 && t < 127){
      int row = lane >> 2, c0 = (lane & 3) * 8;
      const float* xp = x + (size_t)(wgb + row)*4096 + (t+1)*32 + c0;
      f32x4 v0 = *(const f32x4*)xp;
      f32x4 v1 = *(const f32x4*)(xp + 4);
      bf16x8 v;
      v[0]=(__bf16)v0[0]; v[1]=(__bf16)v0[1]; v[2]=(__bf16)v0[2]; v[3]=(__bf16)v0[3];
      v[4]=(__bf16)v1[0]; v[5]=(__bf16)v1[1]; v[6]=(__bf16)v1[2]; v[7]=(__bf16)v1[3];
      *(bf16x8*)&xbuf[cur ^ 1][row*32 + c0] = v;
    }
    // elementwise gate math + h write (C-layout: row = q*4+i, col = w*32+n*16+l)
    #pragma unroll
    for(int n=0;n<2;n++){
      int colc = w*32 + n*16 + l;
      #pragma unroll
      for(int i=0;i<4;i++){
        float fv = sigm (acc[0][n][i] + biasv[0][n]);
        float gv = ftanh(acc[1][n][i] + biasv[1][n]);
        float ov = sigm (acc[2][n][i] + biasv[2][n]);
        float cc = fv * cst[n][i] + ig[n][i] * gv;
        cst[n][i] = cc;
        hbuf[cur ^ 1][(q*4 + i)*264 + colc] = (__bf16)(ov * ftanh(cc));
      }
    }
    __syncthreads();
  }

  // ---------------- head: z1 = [h_last, pm] @ Wd0^T + bd0 ; out = z1 @ Wd1^T + bd1 ----------------
  // h_last is in hbuf[0] (last write at t=127 went to buffer 0)
  f32x4 hd[2];
  {
    f32x4 z4 = {0.f,0.f,0.f,0.f};
    hd[0] = z4; hd[1] = z4;
  }
  #pragma unroll
  for(int kt=0; kt<8; kt++){
    bf16x8 a = *(const bf16x8*)&hbuf[0][l*264 + kt*32 + q*8];
    #pragma unroll
    for(int n=0;n<2;n++){
      int colc = w*32 + n*16 + l;
      const float* p = Wd0 + colc*268 + kt*32 + q*8;
      bf16x8 b;
      #pragma unroll
      for(int j=0;j<8;j++) b[j] = (__bf16)p[j];
      hd[n] = MFMA(a, b, hd[n]);
    }
  }
  { // K-tile 8: pm part (k = 256..267), rest zero
    bf16x8 a;
    #pragma unroll
    for(int j=0;j<8;j++){
      int k2 = q*8 + j;
      a[j] = (__bf16)((k2 < 12) ? pm[(size_t)(wgb + l)*12 + k2] : 0.0f);
    }
    #pragma unroll
    for(int n=0;n<2;n++){
      int colc = w*32 + n*16 + l;
      bf16x8 b;
      #pragma unroll
      for(int j=0;j<8;j++){
        int k2 = q*8 + j;
        b[j] = (__bf16)((k2 < 12) ? Wd0[colc*268 + 256 + k2] : 0.0f);
      }
      hd[n] = MFMA(a, b, hd[n]);
    }
  }
  // z1 to LDS (reuse wlds region; loop barrier guarantees wlds reads are done)
  float* z1 = (float*)wlds;
  #pragma unroll
  for(int n=0;n<2;n++){
    int colc = w*32 + n*16 + l;
    float bb = bd0[colc];
    #pragma unroll
    for(int i=0;i<4;i++) z1[(q*4 + i)*264 + colc] = hd[n][i] + bb;
  }
  __syncthreads();
  {
    int row = tid >> 5, seg = tid & 31;   // 16 rows x 32 partial-segments
    const float* zr = &z1[row*264 + seg*8];
    const float* wr = Wd1 + seg*8;
    float s = 0.0f;
    #pragma unroll
    for(int j=0;j<8;j++) s += zr[j] * wr[j];
    s += __shfl_xor(s, 1);
    s += __shfl_xor(s, 2);
    s += __shfl_xor(s, 4);
    s += __shfl_xor(s, 8);
    s += __shfl_xor(s, 16);
    if(seg == 0) out[wgb + row] = s + bd1[0];
  }
}

extern "C" void kernel_launch(void* const* d_in, const int* in_sizes, int n_in,
                              void* d_out, int out_size, void* d_ws, size_t ws_size,
                              hipStream_t stream) {
  const float* x       = (const float*)d_in[0];
  const float* latlons = (const float*)d_in[1];
  const float* yearly  = (const float*)d_in[2];
  const float* pm      = (const float*)d_in[3];
  const float* Wf_i    = (const float*)d_in[4];
  const float* Wf_h    = (const float*)d_in[5];
  const float* bf_h    = (const float*)d_in[6];
  const float* Wu      = (const float*)d_in[7];
  const float* bu      = (const float*)d_in[8];
  const float* Wg_i    = (const float*)d_in[9];
  const float* Wg_h    = (const float*)d_in[10];
  const float* bg_h    = (const float*)d_in[11];
  const float* Wo_i    = (const float*)d_in[12];
  const float* Wo_h    = (const float*)d_in[13];
  const float* bo_h    = (const float*)d_in[14];
  const float* Wd0     = (const float*)d_in[15];
  const float* bd0     = (const float*)d_in[16];
  const float* Wd1     = (const float*)d_in[17];
  const float* bd1     = (const float*)d_in[18];

  ealstm_kernel<<<dim3(128), dim3(512), 0, stream>>>(
      x, latlons, yearly, pm,
      Wf_i, Wf_h, bf_h, Wu, bu,
      Wg_i, Wg_h, bg_h, Wo_i, Wo_h, bo_h,
      Wd0, bd0, Wd1, bd1,
      (float*)d_out);
}